// Round 4
// baseline (442.663 us; speedup 1.0000x reference)
//
#include <hip/hip_runtime.h>
#include <stdint.h>

typedef unsigned short u16;
typedef __bf16 bf16x8 __attribute__((ext_vector_type(8)));
typedef float f32x4 __attribute__((ext_vector_type(4)));
typedef float f32x16 __attribute__((ext_vector_type(16)));
typedef unsigned short u16x8 __attribute__((ext_vector_type(8)));
typedef unsigned short u16x4 __attribute__((ext_vector_type(4)));

#define MFMA16(a, b, c) __builtin_amdgcn_mfma_f32_16x16x32_bf16(a, b, c, 0, 0, 0)
#define MFMA32(a, b, c) __builtin_amdgcn_mfma_f32_32x32x16_bf16(a, b, c, 0, 0, 0)

static __device__ __forceinline__ u16 f2bf(float f) {
  union { float f; uint32_t u; } v; v.f = f;
  uint32_t r = 0x7FFFu + ((v.u >> 16) & 1u);
  return (u16)((v.u + r) >> 16);
}
static __device__ __forceinline__ float bf2f(u16 h) {
  union { uint32_t u; float f; } v; v.u = ((uint32_t)h) << 16;
  return v.f;
}

static __device__ __forceinline__ void gld_lds16(const u16* g, u16* l) {
  __builtin_amdgcn_global_load_lds(
      (const __attribute__((address_space(1))) void*)g,
      (__attribute__((address_space(3))) void*)l, 16, 0, 0);
}

// ---------------- elementwise cast x f32 -> bf16 ----------------
__global__ __launch_bounds__(256) void cast_f32_to_bf16(
    const float* __restrict__ in, u16* __restrict__ out, int n4) {
  int i = blockIdx.x * blockDim.x + threadIdx.x;
  if (i >= n4) return;
  const float4 v = ((const float4*)in)[i];
  u16x4 o;
  o[0] = f2bf(v.x); o[1] = f2bf(v.y); o[2] = f2bf(v.z); o[3] = f2bf(v.w);
  ((u16x4*)out)[i] = o;
}

// ---------------- transpose + cast: W [R][C] f32 -> Wt [C][R] bf16 ----------------
__global__ __launch_bounds__(256) void transpose_cast(
    const float* __restrict__ W, u16* __restrict__ Wt, int R, int C) {
  __shared__ float tile[32][33];
  const int bx = blockIdx.x * 32;  // C index
  const int by = blockIdx.y * 32;  // R index
  const int tx = threadIdx.x & 31, ty = threadIdx.x >> 5;
#pragma unroll
  for (int i = 0; i < 32; i += 8)
    tile[ty + i][tx] = W[(long)(by + ty + i) * C + bx + tx];
  __syncthreads();
#pragma unroll
  for (int i = 0; i < 32; i += 8)
    Wt[(long)(bx + ty + i) * R + by + tx] = f2bf(tile[tx][ty + i]);
}

// ---------------- RoPE in-place on q (with scale) and k ----------------
__global__ __launch_bounds__(256) void rope_kernel(
    u16* __restrict__ q, u16* __restrict__ k) {
  const int idx = blockIdx.x * blockDim.x + threadIdx.x;
  if (idx >= 4096 * 16 * 64) return;
  const int j = idx & 63;
  const int h = (idx >> 6) & 15;
  const int row = idx >> 10;       // b*2048 + n
  const int npos = row & 2047;
  const float inv_freq = exp2f(-0.20762051f * (float)j);
  const float pos = (float)npos * inv_freq;
  float s, c;
  sincosf(pos, &s, &c);
  const float scale = 0.08838834764831845f;  // 128^-0.5
  const long base = (long)row * 2048 + h * 128 + j;
  float q1 = bf2f(q[base]), q2 = bf2f(q[base + 64]);
  q[base]      = f2bf((q1 * c - q2 * s) * scale);
  q[base + 64] = f2bf((q2 * c + q1 * s) * scale);
  float k1 = bf2f(k[base]), k2 = bf2f(k[base + 64]);
  k[base]      = f2bf(k1 * c - k2 * s);
  k[base + 64] = f2bf(k2 * c + k1 * s);
}

// ---------------- 128x256 pipelined GEMM (T2 swizzle + T3/T4 counted vmcnt + T5) ----
// A [M][K] bf16, Bt [N][K] bf16, K=2048. 8 waves (512 thr): wm=w>>2, wn=w&3.
// Per-wave C: rows wm*64+mf*16, cols wn*64+nf*16 (acc[4][4] f32x4).
// LDS: As[2buf][2kh][128][32], Bs[2buf][2kh][256][32] = 96 KiB, chunk-swizzled:
//   phys_chunk = chunk ^ ((row>>1)&3) (chunk = 16B unit of 8 k-elems) -> 2-way max.
// Staged linearly via global_load_lds with inverse-swizzled SOURCE columns (G21).
// Pipeline per K-tile t (buf=t&1): P1{read kh0 frags; issue B(t+1) x4; vmcnt(4);
//   barrier; 16 MFMA} P2{read kh1 frags; issue A(t+1) x2; vmcnt(1); 16 MFMA;
//   barrier}. In-flight ledger (issue order Bkh0,Bkh1,Akh0,Akh1):
//   pre-P1 invariant: only A(t)kh1 may be outstanding; vmcnt(4) drains it for P2;
//   vmcnt(1) drains B(t+1)+A(t+1)kh0 for next P1. Never 0 in main loop.
template <int OUT_F32>
static __device__ __forceinline__ void gemm_bigtile(
    const u16* __restrict__ A, const u16* __restrict__ Bt,
    const float* __restrict__ bias, void* __restrict__ C,
    u16* As, u16* Bs, const int bx, const int by) {
  constexpr int K = 2048, N = 2048;
  const int tid = threadIdx.x;
  const int w = tid >> 6, lane = tid & 63;
  const int l15 = lane & 15, hi2 = lane >> 4;
  const int wm = w >> 2, wn = w & 3;
  const int row0 = by * 128, col0 = bx * 256;

  // staging sources (inverse-swizzled columns)
  const int cswz = (tid & 3) ^ ((tid >> 3) & 3);
  const u16* srcA  = A + (long)(row0 + (tid >> 2)) * K + cswz * 8;
  const u16* srcB0 = Bt + (long)(col0 + (tid >> 2)) * K + cswz * 8;
  const u16* srcB1 = srcB0 + (long)128 * K;

  // ds_read byte offsets (within a [*][32] kh block)
  int aoff[4], boff[4];
#pragma unroll
  for (int f = 0; f < 4; ++f) {
    const int ra = wm * 64 + f * 16 + l15;
    aoff[f] = ra * 64 + ((hi2 ^ ((ra >> 1) & 3)) << 4);
    const int rb = wn * 64 + f * 16 + l15;
    boff[f] = rb * 64 + ((hi2 ^ ((rb >> 1) & 3)) << 4);
  }
  const char* AsB = (const char*)As;
  const char* BsB = (const char*)Bs;

  f32x4 acc[4][4] = {};

  // prologue: tile 0 -> buf 0 (order: Bkh0, Bkh1, Akh0, Akh1)
  {
    gld_lds16(srcB0, Bs + w * 512);
    gld_lds16(srcB1, Bs + 4096 + w * 512);
    gld_lds16(srcB0 + 32, Bs + 8192 + w * 512);
    gld_lds16(srcB1 + 32, Bs + 8192 + 4096 + w * 512);
    gld_lds16(srcA, As + w * 512);
    gld_lds16(srcA + 32, As + 4096 + w * 512);
  }
  asm volatile("s_waitcnt vmcnt(1)" ::: "memory");
  __builtin_amdgcn_s_barrier();

  constexpr int NT = K / 64;
  for (int t = 0; t < NT - 1; ++t) {
    const int buf = t & 1, nbuf = buf ^ 1;
    const char* Ab = AsB + buf * 16384;
    const char* Bb = BsB + buf * 32768;
    const int g1 = (t + 1) * 64;
    // ---- P1 (kk = 0) ----
    bf16x8 af[4], bfr[4];
#pragma unroll
    for (int f = 0; f < 4; ++f) af[f] = *(const bf16x8*)(Ab + aoff[f]);
#pragma unroll
    for (int f = 0; f < 4; ++f) bfr[f] = *(const bf16x8*)(Bb + boff[f]);
    gld_lds16(srcB0 + g1, Bs + nbuf * 16384 + w * 512);
    gld_lds16(srcB1 + g1, Bs + nbuf * 16384 + 4096 + w * 512);
    gld_lds16(srcB0 + g1 + 32, Bs + nbuf * 16384 + 8192 + w * 512);
    gld_lds16(srcB1 + g1 + 32, Bs + nbuf * 16384 + 8192 + 4096 + w * 512);
    asm volatile("s_waitcnt vmcnt(4)" ::: "memory");
    __builtin_amdgcn_s_barrier();
    __builtin_amdgcn_s_setprio(1);
#pragma unroll
    for (int m = 0; m < 4; ++m)
#pragma unroll
      for (int n = 0; n < 4; ++n) acc[m][n] = MFMA16(af[m], bfr[n], acc[m][n]);
    __builtin_amdgcn_s_setprio(0);
    // ---- P2 (kk = 1) ----
#pragma unroll
    for (int f = 0; f < 4; ++f) af[f] = *(const bf16x8*)(Ab + 8192 + aoff[f]);
#pragma unroll
    for (int f = 0; f < 4; ++f) bfr[f] = *(const bf16x8*)(Bb + 16384 + boff[f]);
    gld_lds16(srcA + g1, As + nbuf * 8192 + w * 512);
    gld_lds16(srcA + g1 + 32, As + nbuf * 8192 + 4096 + w * 512);
    asm volatile("s_waitcnt vmcnt(1)" ::: "memory");
    __builtin_amdgcn_s_setprio(1);
#pragma unroll
    for (int m = 0; m < 4; ++m)
#pragma unroll
      for (int n = 0; n < 4; ++n) acc[m][n] = MFMA16(af[m], bfr[n], acc[m][n]);
    __builtin_amdgcn_s_setprio(0);
    __builtin_amdgcn_s_barrier();   // read-completion fence before next overwrites
  }
  // ---- epilogue tile NT-1 (buf 1), no staging ----
  {
    const char* Ab = AsB + 16384;
    const char* Bb = BsB + 32768;
    bf16x8 af[4], bfr[4];
#pragma unroll
    for (int f = 0; f < 4; ++f) af[f] = *(const bf16x8*)(Ab + aoff[f]);
#pragma unroll
    for (int f = 0; f < 4; ++f) bfr[f] = *(const bf16x8*)(Bb + boff[f]);
    asm volatile("s_waitcnt vmcnt(0)" ::: "memory");
    __builtin_amdgcn_s_barrier();
#pragma unroll
    for (int m = 0; m < 4; ++m)
#pragma unroll
      for (int n = 0; n < 4; ++n) acc[m][n] = MFMA16(af[m], bfr[n], acc[m][n]);
#pragma unroll
    for (int f = 0; f < 4; ++f) af[f] = *(const bf16x8*)(Ab + 8192 + aoff[f]);
#pragma unroll
    for (int f = 0; f < 4; ++f) bfr[f] = *(const bf16x8*)(Bb + 16384 + boff[f]);
#pragma unroll
    for (int m = 0; m < 4; ++m)
#pragma unroll
      for (int n = 0; n < 4; ++n) acc[m][n] = MFMA16(af[m], bfr[n], acc[m][n]);
  }

  // ---- epilogue: bias + store ----
#pragma unroll
  for (int n = 0; n < 4; ++n) {
    const int gcol = col0 + wn * 64 + n * 16 + l15;
    const float bb = bias[gcol];
#pragma unroll
    for (int m = 0; m < 4; ++m) {
      const int grow = row0 + wm * 64 + m * 16 + 4 * hi2;
#pragma unroll
      for (int i = 0; i < 4; ++i) {
        const float v = acc[m][n][i] + bb;
        if (OUT_F32)
          ((float*)C)[(long)(grow + i) * N + gcol] = v;
        else
          ((u16*)C)[(long)(grow + i) * N + gcol] = f2bf(v);
      }
    }
  }
}

__global__ __launch_bounds__(512) void gemm_qkv_kernel(
    const u16* __restrict__ xb,
    const u16* __restrict__ wtq, const u16* __restrict__ wtk, const u16* __restrict__ wtv,
    const float* __restrict__ bq, const float* __restrict__ bk, const float* __restrict__ bv,
    u16* __restrict__ qo, u16* __restrict__ ko, u16* __restrict__ vo) {
  __shared__ u16 As[16384], Bs[32768];
  const u16* Bt; const float* bias; u16* C;
  if (blockIdx.z == 0)      { Bt = wtq; bias = bq; C = qo; }
  else if (blockIdx.z == 1) { Bt = wtk; bias = bk; C = ko; }
  else                      { Bt = wtv; bias = bv; C = vo; }
  gemm_bigtile<0>(xb, Bt, bias, C, As, Bs, blockIdx.x, blockIdx.y);
}

__global__ __launch_bounds__(512) void gemm_out_kernel(
    const u16* __restrict__ ao, const u16* __restrict__ wto,
    const float* __restrict__ bo, float* __restrict__ out) {
  __shared__ u16 As[16384], Bs[32768];
  gemm_bigtile<1>(ao, wto, bo, out, As, Bs, blockIdx.x, blockIdx.y);
}

// ---------------- causal flash attention, swapped-QK^T 32x32 structure ----------------
// (unchanged from round 3 — passing)
__global__ __launch_bounds__(256, 2) void flash_attn_kernel(
    const u16* __restrict__ Q, const u16* __restrict__ K,
    const u16* __restrict__ V, u16* __restrict__ O) {
  __shared__ u16 Ks[2][8192];
  __shared__ char Vs[2][16640];

  const int tid = threadIdx.x;
  const int w = tid >> 6;
  const int lane = tid & 63;
  const int l31 = lane & 31, hi5 = lane >> 5, l15 = lane & 15, bit4 = (lane >> 4) & 1;
  const int qt = 15 - blockIdx.x;            // heavy blocks first
  const int q0 = qt * 128;
  const int bh = blockIdx.y;
  const long plane = (long)(bh >> 4) * 2048 * 2048 + (long)(bh & 15) * 128;
  const u16* Qb = Q + plane;
  const u16* Kb = K + plane;
  const u16* Vb = V + plane;
  const int qrow = q0 + w * 32 + l31;

  // Q B-frags in registers: qf[c] = Q[qrow][c*16 + hi5*8 .. +8]
  bf16x8 qf[8];
#pragma unroll
  for (int c = 0; c < 8; ++c)
    qf[c] = *(const bf16x8*)(Qb + (long)qrow * 2048 + c * 16 + hi5 * 8);

  // staging source offsets (elements within the kv-tile)
  int srcKoff[4], srcVoff[4];
#pragma unroll
  for (int cc = 0; cc < 4; ++cc) {
    const int ci = cc * 256 + tid;
    const int krow = ci >> 4;                 // 16 chunks per 256B row
    const int cL = (ci & 15) * 16;            // linear LDS byte col
    srcKoff[cc] = krow * 2048 + ((cL ^ ((krow & 15) << 4)) >> 1);
    const int dg16 = ci >> 7;                 // V: 128 chunks per d-block
    const int w2 = ci & 127;
    srcVoff[cc] = (w2 >> 1) * 2048 + dg16 * 16 + (w2 & 1) * 8;
  }

  f32x16 ot[4] = {};
  float m = -3e38f, lp = 0.f;
  const int nkt = 2 * qt + 2;
  const int swzk = l15 << 4;
  const int vbase = bit4 * 2080 + hi5 * 256 + l15 * 8;   // 8B/lane chunk stride

  auto STAGE = [&](int buf, int kt1) {
    const long koff = (long)kt1 * 131072;     // 64 rows * 2048 elems
#pragma unroll
    for (int cc = 0; cc < 4; ++cc) {
      gld_lds16(Kb + koff + srcKoff[cc], &Ks[buf][cc * 2048 + w * 512]);
      const int ci0 = cc * 256 + w * 64;
      gld_lds16(Vb + koff + srcVoff[cc],
                (u16*)&Vs[buf][(ci0 >> 7) * 2080 + (ci0 & 127) * 16]);
    }
  };

  STAGE(0, 0);
  for (int kt = 0; kt < nkt; ++kt) {
    __syncthreads();                          // drains prev STAGE (vmcnt0) + sync
    if (kt + 1 < nkt) STAGE((kt + 1) & 1, kt + 1);
    const int kv0 = kt * 64;
    if (kv0 > q0 + w * 32 + 31) continue;     // wave fully masked: skip compute

    const char* KT = (const char*)Ks[kt & 1];
    const char* VT = Vs[kt & 1];

    // ---- S^T = K Q^T (two 32-kv groups) ----
    f32x16 sa[2] = {};
#pragma unroll
    for (int g = 0; g < 2; ++g) {
      const int rowb = (g * 32 + l31) * 256;
#pragma unroll
      for (int c = 0; c < 8; ++c) {
        const int ab = rowb + ((c * 32 + hi5 * 16) ^ swzk);
        const bf16x8 kf = *(const bf16x8*)(KT + ab);
        sa[g] = MFMA32(kf, qf[c], sa[g]);
      }
    }

    // ---- causal mask (S^T: row kv = (r&3)+8*(r>>2)+4*hi5, col q = l31) ----
    if (kv0 + 63 > q0 + w * 32) {
#pragma unroll
      for (int g = 0; g < 2; ++g)
#pragma unroll
        for (int r = 0; r < 16; ++r) {
          const int kv = kv0 + g * 32 + (r & 3) + 8 * (r >> 2) + 4 * hi5;
          if (kv > qrow) sa[g][r] = -1e30f;
        }
    }

    // ---- online softmax, fully in-register (lane pair l <-> l^32 shares q) ----
    float pm = -3e38f;
#pragma unroll
    for (int g = 0; g < 2; ++g)
#pragma unroll
      for (int r = 0; r < 16; ++r) pm = fmaxf(pm, sa[g][r]);
    pm = fmaxf(pm, __shfl_xor(pm, 32));
    const float mnew = fmaxf(m, pm);
    const float alpha = __expf(m - mnew);
    float psum = 0.f;
#pragma unroll
    for (int g = 0; g < 2; ++g)
#pragma unroll
      for (int r = 0; r < 16; ++r) {
        const float pv = __expf(sa[g][r] - mnew);
        sa[g][r] = pv;
        psum += pv;
      }
    lp = lp * alpha + psum;
    m = mnew;
#pragma unroll
    for (int dg = 0; dg < 4; ++dg) ot[dg] *= alpha;

    // ---- P^T B-frags: cvt_pk pairs + cross-half exchange ----
    uint32_t pk[2][8];
#pragma unroll
    for (int g = 0; g < 2; ++g)
#pragma unroll
      for (int k2 = 0; k2 < 8; ++k2)
        asm("v_cvt_pk_bf16_f32 %0, %1, %2"
            : "=v"(pk[g][k2]) : "v"(sa[g][2 * k2]), "v"(sa[g][2 * k2 + 1]));

    bf16x8 pfrag[4];
#pragma unroll
    for (int kc = 0; kc < 4; ++kc) {
      const int g = kc >> 1, b = 4 * (kc & 1);
      const uint32_t lo0 = pk[g][b],     lo1 = pk[g][b + 1];
      const uint32_t hh0 = pk[g][b + 2], hh1 = pk[g][b + 3];
      const uint32_t s0v = hi5 ? lo0 : hh0;   // send opposite-half block to pair
      const uint32_t s1v = hi5 ? lo1 : hh1;
      const uint32_t r0 = (uint32_t)__shfl_xor((int)s0v, 32);
      const uint32_t r1 = (uint32_t)__shfl_xor((int)s1v, 32);
      union { uint32_t u[4]; bf16x8 v; } fu;
      fu.u[0] = hi5 ? r0 : lo0;
      fu.u[1] = hi5 ? r1 : lo1;
      fu.u[2] = hi5 ? hh0 : r0;
      fu.u[3] = hi5 ? hh1 : r1;
      pfrag[kc] = fu.v;
    }

    // ---- O^T += V^T P^T  (V^T A-frags via hw transpose read) ----
#pragma unroll
    for (int dg = 0; dg < 4; ++dg) {
      unsigned long long t[8];
#pragma unroll
      for (int kc = 0; kc < 4; ++kc)
#pragma unroll
        for (int r = 0; r < 2; ++r) {
          const uint32_t a = (uint32_t)(size_t)VT + (uint32_t)(vbase + dg * 4160 + kc * 512 + r * 128);
          asm volatile("ds_read_b64_tr_b16 %0, %1" : "=v"(t[kc * 2 + r]) : "v"(a));
        }
      asm volatile("s_waitcnt lgkmcnt(0)" ::: "memory");
      __builtin_amdgcn_sched_barrier(0);
#pragma unroll
      for (int kc = 0; kc < 4; ++kc) {
        union { unsigned long long q[2]; bf16x8 v; } vu;
        vu.q[0] = t[kc * 2]; vu.q[1] = t[kc * 2 + 1];
        ot[dg] = MFMA32(vu.v, pfrag[kc], ot[dg]);
      }
    }
  }

  // ---- epilogue: normalize, write O^T -> O[q][d] (8B packs) ----
  const float lt = lp + __shfl_xor(lp, 32);
  const float inv = 1.0f / lt;
  u16* Ob = (u16*)O + plane;
#pragma unroll
  for (int dg = 0; dg < 4; ++dg)
#pragma unroll
    for (int rq = 0; rq < 4; ++rq) {
      u16x4 pk4;
#pragma unroll
      for (int j = 0; j < 4; ++j) pk4[j] = f2bf(ot[dg][rq * 4 + j] * inv);
      *(u16x4*)(Ob + (long)qrow * 2048 + dg * 32 + 8 * rq + 4 * hi5) = pk4;
    }
}

// ---------------- launch ----------------
extern "C" void kernel_launch(void* const* d_in, const int* in_sizes, int n_in,
                              void* d_out, int out_size, void* d_ws, size_t ws_size,
                              hipStream_t stream) {
  const float* x  = (const float*)d_in[0];
  const float* Wq = (const float*)d_in[1];
  const float* bq = (const float*)d_in[2];
  const float* Wk = (const float*)d_in[3];
  const float* bk = (const float*)d_in[4];
  const float* Wv = (const float*)d_in[5];
  const float* bv = (const float*)d_in[6];
  const float* Wo = (const float*)d_in[7];
  const float* bo = (const float*)d_in[8];
  float* out = (float*)d_out;

  char* ws = (char*)d_ws;
  size_t off = 0;
  u16* xb   = (u16*)(ws + off); off += (size_t)4096 * 2048 * 2;
  u16* wtq  = (u16*)(ws + off); off += (size_t)2048 * 2048 * 2;
  u16* wtk  = (u16*)(ws + off); off += (size_t)2048 * 2048 * 2;
  u16* wtv  = (u16*)(ws + off); off += (size_t)2048 * 2048 * 2;
  u16* wto  = (u16*)(ws + off); off += (size_t)2048 * 2048 * 2;
  u16* qlin = (u16*)(ws + off); off += (size_t)4096 * 2048 * 2;
  u16* klin = (u16*)(ws + off); off += (size_t)4096 * 2048 * 2;
  u16* vlin = (u16*)(ws + off); off += (size_t)4096 * 2048 * 2;
  u16* aout = (u16*)(ws + off); off += (size_t)4096 * 2048 * 2;
  (void)ws_size; (void)in_sizes; (void)n_in; (void)out_size;

  cast_f32_to_bf16<<<dim3(8192), dim3(256), 0, stream>>>(x, xb, 4096 * 2048 / 4);
  dim3 tgrid(64, 64);
  transpose_cast<<<tgrid, dim3(256), 0, stream>>>(Wq, wtq, 2048, 2048);
  transpose_cast<<<tgrid, dim3(256), 0, stream>>>(Wk, wtk, 2048, 2048);
  transpose_cast<<<tgrid, dim3(256), 0, stream>>>(Wv, wtv, 2048, 2048);
  transpose_cast<<<tgrid, dim3(256), 0, stream>>>(Wo, wto, 2048, 2048);

  gemm_qkv_kernel<<<dim3(8, 32, 3), dim3(512), 0, stream>>>(
      xb, wtq, wtk, wtv, bq, bk, bv, qlin, klin, vlin);
  rope_kernel<<<dim3(16384), dim3(256), 0, stream>>>(qlin, klin);
  flash_attn_kernel<<<dim3(16, 32), dim3(256), 0, stream>>>(qlin, klin, vlin, aout);
  gemm_out_kernel<<<dim3(8, 32), dim3(512), 0, stream>>>(aout, wto, bo, out);
}

// Round 5
// 419.963 us; speedup vs baseline: 1.0541x; 1.0541x over previous
//
#include <hip/hip_runtime.h>
#include <stdint.h>

typedef unsigned short u16;
typedef __bf16 bf16x8 __attribute__((ext_vector_type(8)));
typedef float f32x4 __attribute__((ext_vector_type(4)));
typedef float f32x16 __attribute__((ext_vector_type(16)));
typedef unsigned short u16x8 __attribute__((ext_vector_type(8)));
typedef unsigned short u16x4 __attribute__((ext_vector_type(4)));

#define MFMA16(a, b, c) __builtin_amdgcn_mfma_f32_16x16x32_bf16(a, b, c, 0, 0, 0)
#define MFMA32(a, b, c) __builtin_amdgcn_mfma_f32_32x32x16_bf16(a, b, c, 0, 0, 0)

static __device__ __forceinline__ u16 f2bf(float f) {
  union { float f; uint32_t u; } v; v.f = f;
  uint32_t r = 0x7FFFu + ((v.u >> 16) & 1u);
  return (u16)((v.u + r) >> 16);
}
static __device__ __forceinline__ float bf2f(u16 h) {
  union { uint32_t u; float f; } v; v.u = ((uint32_t)h) << 16;
  return v.f;
}

static __device__ __forceinline__ void gld_lds16(const u16* g, u16* l) {
  __builtin_amdgcn_global_load_lds(
      (const __attribute__((address_space(1))) void*)g,
      (__attribute__((address_space(3))) void*)l, 16, 0, 0);
}

// ---------------- elementwise cast x f32 -> bf16 ----------------
__global__ __launch_bounds__(256) void cast_f32_to_bf16(
    const float* __restrict__ in, u16* __restrict__ out, int n4) {
  int i = blockIdx.x * blockDim.x + threadIdx.x;
  if (i >= n4) return;
  const float4 v = ((const float4*)in)[i];
  u16x4 o;
  o[0] = f2bf(v.x); o[1] = f2bf(v.y); o[2] = f2bf(v.z); o[3] = f2bf(v.w);
  ((u16x4*)out)[i] = o;
}

// ---------------- transpose + cast: W [R][C] f32 -> Wt [C][R] bf16 ----------------
__global__ __launch_bounds__(256) void transpose_cast(
    const float* __restrict__ W, u16* __restrict__ Wt, int R, int C) {
  __shared__ float tile[32][33];
  const int bx = blockIdx.x * 32;  // C index
  const int by = blockIdx.y * 32;  // R index
  const int tx = threadIdx.x & 31, ty = threadIdx.x >> 5;
#pragma unroll
  for (int i = 0; i < 32; i += 8)
    tile[ty + i][tx] = W[(long)(by + ty + i) * C + bx + tx];
  __syncthreads();
#pragma unroll
  for (int i = 0; i < 32; i += 8)
    Wt[(long)(bx + ty + i) * R + by + tx] = f2bf(tile[tx][ty + i]);
}

// ---------------- RoPE in-place on q (with scale) and k ----------------
__global__ __launch_bounds__(256) void rope_kernel(
    u16* __restrict__ q, u16* __restrict__ k) {
  const int idx = blockIdx.x * blockDim.x + threadIdx.x;
  if (idx >= 4096 * 16 * 64) return;
  const int j = idx & 63;
  const int h = (idx >> 6) & 15;
  const int row = idx >> 10;       // b*2048 + n
  const int npos = row & 2047;
  const float inv_freq = exp2f(-0.20762051f * (float)j);
  const float pos = (float)npos * inv_freq;
  float s, c;
  sincosf(pos, &s, &c);
  const float scale = 0.08838834764831845f;  // 128^-0.5
  const long base = (long)row * 2048 + h * 128 + j;
  float q1 = bf2f(q[base]), q2 = bf2f(q[base + 64]);
  q[base]      = f2bf((q1 * c - q2 * s) * scale);
  q[base + 64] = f2bf((q2 * c + q1 * s) * scale);
  float k1 = bf2f(k[base]), k2 = bf2f(k[base + 64]);
  k[base]      = f2bf(k1 * c - k2 * s);
  k[base + 64] = f2bf(k2 * c + k1 * s);
}

// ---------------- 256-row deep-pipelined GEMM (m201 cadence) ----------------
// A [M][K] bf16, Bt [N][K] bf16, K=2048. 8 waves (512 thr): wm=w>>2 (2 M-waves
// of 128 rows), wn=w&3 (4 N-waves of BN/4 cols). acc[8][NF] f32x4.
// BK=32 (64 B rows, 4 chunks of 16 B), chunk-swizzled phys = c ^ ((row>>1)&3)
// -> 2-way bank aliasing (free). Staged via global_load_lds with inverse-
// swizzled SOURCE chunk (G21 both-sides).
// 4 LDS buffers (tile tt -> buf tt&3). Prologue issues tiles 0..2; during tile
// t issue tile t+3 (overwrites buf of t-1, safe after entry barrier). Entry
// wait: vmcnt(2*LPT) keeps 2 tiles in flight (LPT loads/tile), never drains
// until the 3-tile epilogue peel (2*LPT, LPT, 0).
template <int OUT_F32, int BN>   // BN = 256 (LPT=4) or 128 (LPT=3)
static __device__ __forceinline__ void gemm256(
    const u16* __restrict__ A, const u16* __restrict__ Bt,
    const float* __restrict__ bias, void* __restrict__ C,
    char* ldsA, char* ldsB, const int bm, const int bn) {
  constexpr int K = 2048, N = 2048, NT = 64;
  constexpr int NF = BN / 64;        // n-frags per wave: 4 or 2
  constexpr int NBI = BN / 128;      // B gld issues per tile: 2 or 1
  const int tid = threadIdx.x;
  const int w = tid >> 6, lane = tid & 63;
  const int l15 = lane & 15, hi2 = (lane >> 4) & 3;
  const int wm = w >> 2, wn = w & 3;
  const int row0 = bm * 256, col0 = bn * BN;

  // staging sources: row = tid>>2 within 128-row issue, inverse-swizzled chunk
  const int srcch = ((tid & 3) ^ ((tid >> 3) & 3)) * 8;
  const u16* sA0 = A + (long)(row0 + (tid >> 2)) * K + srcch;
  const u16* sA1 = sA0 + (long)128 * K;
  const u16* sB0 = Bt + (long)(col0 + (tid >> 2)) * K + srcch;
  const u16* sB1 = sB0 + (long)128 * K;

  // frag ds_read byte offsets within a buffer
  int aoff[8], boff[NF];
#pragma unroll
  for (int f = 0; f < 8; ++f) {
    const int r = wm * 128 + f * 16 + l15;
    aoff[f] = r * 64 + ((hi2 ^ ((r >> 1) & 3)) << 4);
  }
#pragma unroll
  for (int n = 0; n < NF; ++n) {
    const int r = wn * (BN / 4) + n * 16 + l15;
    boff[n] = r * 64 + ((hi2 ^ ((r >> 1) & 3)) << 4);
  }

  f32x4 acc[8][NF] = {};

  auto ISSUE = [&](int tt) {
    const long kof = (long)tt * 32;
    const int b = tt & 3;
    u16* Ad = (u16*)(ldsA + b * 16384) + w * 512;
    gld_lds16(sA0 + kof, Ad);
    gld_lds16(sA1 + kof, Ad + 4096);
    u16* Bd = (u16*)(ldsB + b * (NBI * 8192)) + w * 512;
    gld_lds16(sB0 + kof, Bd);
    if constexpr (NBI == 2) gld_lds16(sB1 + kof, Bd + 4096);
  };

  auto BODY = [&](int buf, bool issue, int tt) {
    const char* Ab = ldsA + buf * 16384;
    const char* Bb = ldsB + buf * (NBI * 8192);
    bf16x8 af[8], bfr[NF];
#pragma unroll
    for (int f = 0; f < 8; ++f) af[f] = *(const bf16x8*)(Ab + aoff[f]);
#pragma unroll
    for (int n = 0; n < NF; ++n) bfr[n] = *(const bf16x8*)(Bb + boff[n]);
    if (issue) ISSUE(tt);
    __builtin_amdgcn_s_setprio(1);
#pragma unroll
    for (int f = 0; f < 8; ++f)
#pragma unroll
      for (int n = 0; n < NF; ++n) acc[f][n] = MFMA16(af[f], bfr[n], acc[f][n]);
    __builtin_amdgcn_s_setprio(0);
  };

#define WAIT_MAIN()                                                        \
  do {                                                                     \
    if constexpr (BN == 256) asm volatile("s_waitcnt vmcnt(8)" ::: "memory"); \
    else asm volatile("s_waitcnt vmcnt(6)" ::: "memory");                  \
  } while (0)
#define WAIT_HALF()                                                        \
  do {                                                                     \
    if constexpr (BN == 256) asm volatile("s_waitcnt vmcnt(4)" ::: "memory"); \
    else asm volatile("s_waitcnt vmcnt(3)" ::: "memory");                  \
  } while (0)
#define BARSB()                     \
  __builtin_amdgcn_s_barrier();     \
  __builtin_amdgcn_sched_barrier(0)

  ISSUE(0); ISSUE(1); ISSUE(2);

#pragma unroll 4
  for (int t = 0; t < NT - 4; ++t) {   // t = 0..59, issues tiles 3..62
    WAIT_MAIN(); BARSB();
    BODY(t & 3, true, t + 3);
  }
  WAIT_MAIN(); BARSB(); BODY(0, true, 63);   // t=60, issues tile 63
  WAIT_MAIN(); BARSB(); BODY(1, false, 0);   // t=61
  WAIT_HALF(); BARSB(); BODY(2, false, 0);   // t=62
  asm volatile("s_waitcnt vmcnt(0)" ::: "memory");
  BARSB(); BODY(3, false, 0);                // t=63
#undef WAIT_MAIN
#undef WAIT_HALF
#undef BARSB

  // epilogue: bias + store (D row = base + 4*hi2 + i, col = base + l15)
#pragma unroll
  for (int n = 0; n < NF; ++n) {
    const int gcol = col0 + wn * (BN / 4) + n * 16 + l15;
    const float bb = bias[gcol];
#pragma unroll
    for (int f = 0; f < 8; ++f) {
      const int grow = row0 + wm * 128 + f * 16 + 4 * hi2;
#pragma unroll
      for (int i = 0; i < 4; ++i) {
        const float v = acc[f][n][i] + bb;
        if (OUT_F32)
          ((float*)C)[(long)(grow + i) * N + gcol] = v;
        else
          ((u16*)C)[(long)(grow + i) * N + gcol] = f2bf(v);
      }
    }
  }
}

__global__ __launch_bounds__(512, 2) void gemm_qkv_kernel(
    const u16* __restrict__ xb,
    const u16* __restrict__ wtq, const u16* __restrict__ wtk, const u16* __restrict__ wtv,
    const float* __restrict__ bq, const float* __restrict__ bk, const float* __restrict__ bv,
    u16* __restrict__ qo, u16* __restrict__ ko, u16* __restrict__ vo) {
  __shared__ char ldsA[65536], ldsB[65536];
  const int id = blockIdx.x;                  // 128 blocks per z-slice
  const int swz = (id & 7) * 16 + (id >> 3);  // XCD-contiguous chunks (128%8==0)
  const int bm = swz >> 3, bn = swz & 7;      // 16 x 8 tiles of 256x256
  const u16* Bt; const float* bias; u16* C;
  if (blockIdx.y == 0)      { Bt = wtq; bias = bq; C = qo; }
  else if (blockIdx.y == 1) { Bt = wtk; bias = bk; C = ko; }
  else                      { Bt = wtv; bias = bv; C = vo; }
  gemm256<0, 256>(xb, Bt, bias, C, ldsA, ldsB, bm, bn);
}

__global__ __launch_bounds__(512, 2) void gemm_out_kernel(
    const u16* __restrict__ ao, const u16* __restrict__ wto,
    const float* __restrict__ bo, float* __restrict__ out) {
  __shared__ char ldsA[65536], ldsB[32768];
  const int id = blockIdx.x;                  // 256 blocks = 1/CU
  const int swz = (id & 7) * 32 + (id >> 3);  // 256%8==0 bijective
  const int bm = swz >> 4, bn = swz & 15;     // 16 x 16 tiles of 256x128
  gemm256<1, 128>(ao, wto, bo, out, ldsA, ldsB, bm, bn);
}

// ---------------- causal flash attention, swapped-QK^T 32x32 structure ----------------
// (unchanged from round 3 — passing)
__global__ __launch_bounds__(256, 2) void flash_attn_kernel(
    const u16* __restrict__ Q, const u16* __restrict__ K,
    const u16* __restrict__ V, u16* __restrict__ O) {
  __shared__ u16 Ks[2][8192];
  __shared__ char Vs[2][16640];

  const int tid = threadIdx.x;
  const int w = tid >> 6;
  const int lane = tid & 63;
  const int l31 = lane & 31, hi5 = lane >> 5, l15 = lane & 15, bit4 = (lane >> 4) & 1;
  const int qt = 15 - blockIdx.x;            // heavy blocks first
  const int q0 = qt * 128;
  const int bh = blockIdx.y;
  const long plane = (long)(bh >> 4) * 2048 * 2048 + (long)(bh & 15) * 128;
  const u16* Qb = Q + plane;
  const u16* Kb = K + plane;
  const u16* Vb = V + plane;
  const int qrow = q0 + w * 32 + l31;

  // Q B-frags in registers: qf[c] = Q[qrow][c*16 + hi5*8 .. +8]
  bf16x8 qf[8];
#pragma unroll
  for (int c = 0; c < 8; ++c)
    qf[c] = *(const bf16x8*)(Qb + (long)qrow * 2048 + c * 16 + hi5 * 8);

  // staging source offsets (elements within the kv-tile)
  int srcKoff[4], srcVoff[4];
#pragma unroll
  for (int cc = 0; cc < 4; ++cc) {
    const int ci = cc * 256 + tid;
    const int krow = ci >> 4;                 // 16 chunks per 256B row
    const int cL = (ci & 15) * 16;            // linear LDS byte col
    srcKoff[cc] = krow * 2048 + ((cL ^ ((krow & 15) << 4)) >> 1);
    const int dg16 = ci >> 7;                 // V: 128 chunks per d-block
    const int w2 = ci & 127;
    srcVoff[cc] = (w2 >> 1) * 2048 + dg16 * 16 + (w2 & 1) * 8;
  }

  f32x16 ot[4] = {};
  float m = -3e38f, lp = 0.f;
  const int nkt = 2 * qt + 2;
  const int swzk = l15 << 4;
  const int vbase = bit4 * 2080 + hi5 * 256 + l15 * 8;   // 8B/lane chunk stride

  auto STAGE = [&](int buf, int kt1) {
    const long koff = (long)kt1 * 131072;     // 64 rows * 2048 elems
#pragma unroll
    for (int cc = 0; cc < 4; ++cc) {
      gld_lds16(Kb + koff + srcKoff[cc], &Ks[buf][cc * 2048 + w * 512]);
      const int ci0 = cc * 256 + w * 64;
      gld_lds16(Vb + koff + srcVoff[cc],
                (u16*)&Vs[buf][(ci0 >> 7) * 2080 + (ci0 & 127) * 16]);
    }
  };

  STAGE(0, 0);
  for (int kt = 0; kt < nkt; ++kt) {
    __syncthreads();                          // drains prev STAGE (vmcnt0) + sync
    if (kt + 1 < nkt) STAGE((kt + 1) & 1, kt + 1);
    const int kv0 = kt * 64;
    if (kv0 > q0 + w * 32 + 31) continue;     // wave fully masked: skip compute

    const char* KT = (const char*)Ks[kt & 1];
    const char* VT = Vs[kt & 1];

    // ---- S^T = K Q^T (two 32-kv groups) ----
    f32x16 sa[2] = {};
#pragma unroll
    for (int g = 0; g < 2; ++g) {
      const int rowb = (g * 32 + l31) * 256;
#pragma unroll
      for (int c = 0; c < 8; ++c) {
        const int ab = rowb + ((c * 32 + hi5 * 16) ^ swzk);
        const bf16x8 kf = *(const bf16x8*)(KT + ab);
        sa[g] = MFMA32(kf, qf[c], sa[g]);
      }
    }

    // ---- causal mask (S^T: row kv = (r&3)+8*(r>>2)+4*hi5, col q = l31) ----
    if (kv0 + 63 > q0 + w * 32) {
#pragma unroll
      for (int g = 0; g < 2; ++g)
#pragma unroll
        for (int r = 0; r < 16; ++r) {
          const int kv = kv0 + g * 32 + (r & 3) + 8 * (r >> 2) + 4 * hi5;
          if (kv > qrow) sa[g][r] = -1e30f;
        }
    }

    // ---- online softmax, fully in-register (lane pair l <-> l^32 shares q) ----
    float pm = -3e38f;
#pragma unroll
    for (int g = 0; g < 2; ++g)
#pragma unroll
      for (int r = 0; r < 16; ++r) pm = fmaxf(pm, sa[g][r]);
    pm = fmaxf(pm, __shfl_xor(pm, 32));
    const float mnew = fmaxf(m, pm);
    const float alpha = __expf(m - mnew);
    float psum = 0.f;
#pragma unroll
    for (int g = 0; g < 2; ++g)
#pragma unroll
      for (int r = 0; r < 16; ++r) {
        const float pv = __expf(sa[g][r] - mnew);
        sa[g][r] = pv;
        psum += pv;
      }
    lp = lp * alpha + psum;
    m = mnew;
#pragma unroll
    for (int dg = 0; dg < 4; ++dg) ot[dg] *= alpha;

    // ---- P^T B-frags: cvt_pk pairs + cross-half exchange ----
    uint32_t pk[2][8];
#pragma unroll
    for (int g = 0; g < 2; ++g)
#pragma unroll
      for (int k2 = 0; k2 < 8; ++k2)
        asm("v_cvt_pk_bf16_f32 %0, %1, %2"
            : "=v"(pk[g][k2]) : "v"(sa[g][2 * k2]), "v"(sa[g][2 * k2 + 1]));

    bf16x8 pfrag[4];
#pragma unroll
    for (int kc = 0; kc < 4; ++kc) {
      const int g = kc >> 1, b = 4 * (kc & 1);
      const uint32_t lo0 = pk[g][b],     lo1 = pk[g][b + 1];
      const uint32_t hh0 = pk[g][b + 2], hh1 = pk[g][b + 3];
      const uint32_t s0v = hi5 ? lo0 : hh0;   // send opposite-half block to pair
      const uint32_t s1v = hi5 ? lo1 : hh1;
      const uint32_t r0 = (uint32_t)__shfl_xor((int)s0v, 32);
      const uint32_t r1 = (uint32_t)__shfl_xor((int)s1v, 32);
      union { uint32_t u[4]; bf16x8 v; } fu;
      fu.u[0] = hi5 ? r0 : lo0;
      fu.u[1] = hi5 ? r1 : lo1;
      fu.u[2] = hi5 ? hh0 : r0;
      fu.u[3] = hi5 ? hh1 : r1;
      pfrag[kc] = fu.v;
    }

    // ---- O^T += V^T P^T  (V^T A-frags via hw transpose read) ----
#pragma unroll
    for (int dg = 0; dg < 4; ++dg) {
      unsigned long long t[8];
#pragma unroll
      for (int kc = 0; kc < 4; ++kc)
#pragma unroll
        for (int r = 0; r < 2; ++r) {
          const uint32_t a = (uint32_t)(size_t)VT + (uint32_t)(vbase + dg * 4160 + kc * 512 + r * 128);
          asm volatile("ds_read_b64_tr_b16 %0, %1" : "=v"(t[kc * 2 + r]) : "v"(a));
        }
      asm volatile("s_waitcnt lgkmcnt(0)" ::: "memory");
      __builtin_amdgcn_sched_barrier(0);
#pragma unroll
      for (int kc = 0; kc < 4; ++kc) {
        union { unsigned long long q[2]; bf16x8 v; } vu;
        vu.q[0] = t[kc * 2]; vu.q[1] = t[kc * 2 + 1];
        ot[dg] = MFMA32(vu.v, pfrag[kc], ot[dg]);
      }
    }
  }

  // ---- epilogue: normalize, write O^T -> O[q][d] (8B packs) ----
  const float lt = lp + __shfl_xor(lp, 32);
  const float inv = 1.0f / lt;
  u16* Ob = (u16*)O + plane;
#pragma unroll
  for (int dg = 0; dg < 4; ++dg)
#pragma unroll
    for (int rq = 0; rq < 4; ++rq) {
      u16x4 pk4;
#pragma unroll
      for (int j = 0; j < 4; ++j) pk4[j] = f2bf(ot[dg][rq * 4 + j] * inv);
      *(u16x4*)(Ob + (long)qrow * 2048 + dg * 32 + 8 * rq + 4 * hi5) = pk4;
    }
}

// ---------------- launch ----------------
extern "C" void kernel_launch(void* const* d_in, const int* in_sizes, int n_in,
                              void* d_out, int out_size, void* d_ws, size_t ws_size,
                              hipStream_t stream) {
  const float* x  = (const float*)d_in[0];
  const float* Wq = (const float*)d_in[1];
  const float* bq = (const float*)d_in[2];
  const float* Wk = (const float*)d_in[3];
  const float* bk = (const float*)d_in[4];
  const float* Wv = (const float*)d_in[5];
  const float* bv = (const float*)d_in[6];
  const float* Wo = (const float*)d_in[7];
  const float* bo = (const float*)d_in[8];
  float* out = (float*)d_out;

  char* ws = (char*)d_ws;
  size_t off = 0;
  u16* xb   = (u16*)(ws + off); off += (size_t)4096 * 2048 * 2;
  u16* wtq  = (u16*)(ws + off); off += (size_t)2048 * 2048 * 2;
  u16* wtk  = (u16*)(ws + off); off += (size_t)2048 * 2048 * 2;
  u16* wtv  = (u16*)(ws + off); off += (size_t)2048 * 2048 * 2;
  u16* wto  = (u16*)(ws + off); off += (size_t)2048 * 2048 * 2;
  u16* qlin = (u16*)(ws + off); off += (size_t)4096 * 2048 * 2;
  u16* klin = (u16*)(ws + off); off += (size_t)4096 * 2048 * 2;
  u16* vlin = (u16*)(ws + off); off += (size_t)4096 * 2048 * 2;
  u16* aout = (u16*)(ws + off); off += (size_t)4096 * 2048 * 2;
  (void)ws_size; (void)in_sizes; (void)n_in; (void)out_size;

  cast_f32_to_bf16<<<dim3(8192), dim3(256), 0, stream>>>(x, xb, 4096 * 2048 / 4);
  dim3 tgrid(64, 64);
  transpose_cast<<<tgrid, dim3(256), 0, stream>>>(Wq, wtq, 2048, 2048);
  transpose_cast<<<tgrid, dim3(256), 0, stream>>>(Wk, wtk, 2048, 2048);
  transpose_cast<<<tgrid, dim3(256), 0, stream>>>(Wv, wtv, 2048, 2048);
  transpose_cast<<<tgrid, dim3(256), 0, stream>>>(Wo, wto, 2048, 2048);

  gemm_qkv_kernel<<<dim3(128, 3), dim3(512), 0, stream>>>(
      xb, wtq, wtk, wtv, bq, bk, bv, qlin, klin, vlin);
  rope_kernel<<<dim3(16384), dim3(256), 0, stream>>>(qlin, klin);
  flash_attn_kernel<<<dim3(16, 32), dim3(256), 0, stream>>>(qlin, klin, vlin, aout);
  gemm_out_kernel<<<dim3(256), dim3(512), 0, stream>>>(aout, wto, bo, out);
}